// Round 11
// baseline (834.534 us; speedup 1.0000x reference)
//
#include <hip/hip_runtime.h>
#include <stdint.h>

#define TSTEPS 1024
#define L2E 1.4426950408889634f

typedef float v2f __attribute__((ext_vector_type(2)));
typedef float v4f __attribute__((ext_vector_type(4)));

__device__ __forceinline__ float rcpf_(float v) { return __builtin_amdgcn_rcpf(v); }
__device__ __forceinline__ float ex2(float v) { return __builtin_amdgcn_exp2f(v); }
#define PKFMA(a, b, c) __builtin_elementwise_fma((a), (b), (c))

// ONLY symmetric (xor) quad_perm controls — HW-proven in R5-R9.
template <int CTRL>
__device__ __forceinline__ float dppf(float v) {
    return __int_as_float(__builtin_amdgcn_update_dpp(
        0, __float_as_int(v), CTRL, 0xF, 0xF, true));
}
// quad sum (butterfly xor1, xor2) with per-lane bias folded into the first add
__device__ __forceinline__ float q4sumb(v2f a, float b) {
    float s = (a.x + a.y) + b;
    s += dppf<0xB1>(s);  // xor 1
    s += dppf<0x4E>(s);  // xor 2
    return s;
}

// Opaque loads: value is asm-produced -> cannot be rematerialized as a load.
__device__ __forceinline__ v2f ldg2(const float* p) {
    v2f r; uint64_t a = (uint64_t)p;
    asm volatile("global_load_dwordx2 %0, %1, off\n\ts_waitcnt vmcnt(0)"
                 : "=v"(r) : "v"(a));
    return r;
}
__device__ __forceinline__ float ldg1(const float* p) {
    float r; uint64_t a = (uint64_t)p;
    asm volatile("global_load_dword %0, %1, off\n\ts_waitcnt vmcnt(0)"
                 : "=v"(r) : "v"(a));
    return r;
}

// 2- and 4-pair pk-FMA dot chains (zero seed)
#define CH2(W, H) PKFMA(W[1], H[1], W[0] * H[0])
#define CH4(Wa, Ha, Wb, Hb) PKFMA(Wa[1], Ha[1], PKFMA(Wa[0], Ha[0], CH2(Wb, Hb)))

__global__ __launch_bounds__(256, 4) void gru3_r11(
    const float* __restrict__ x,      // [4096,1024,1]
    const float* __restrict__ w_ih0,  // [48,1]
    const float* __restrict__ w_ih12, // [2,48,16]
    const float* __restrict__ w_hh,   // [3,48,16]
    const float* __restrict__ b_ih,   // [3,48]
    const float* __restrict__ b_hh,   // [3,48]
    const float* __restrict__ fc_w,   // [5,16]
    const float* __restrict__ fc_b,   // [5]
    float* __restrict__ out)          // [4096,5]
{
    __shared__ float xs[4][TSTEPS];  // 16 KB: one x row per wave
    __shared__ float hb[4][4][16];   // [wave][layer0..2 + dummy][unit]

    const int lane = threadIdx.x & 63;
    const int slot = threadIdx.x >> 6;  // wave in block = sequence slot
    const int u = lane >> 2;            // hidden unit (0..15)
    const int c = lane & 3;             // col group (4 cols) + gate/layer role
    const int seq = blockIdx.x * 4 + slot;
    const bool codd = (c & 1);
    const bool g1m = (c == 1), g2m = (c == 2), g3m = (c == 3);

    // ---- stage x (coalesced float4) + zero h buffers
    {
        const float4* xg = (const float4*)(x + (size_t)blockIdx.x * 4 * TSTEPS);
        float4* xs4 = (float4*)&xs[0][0];
#pragma unroll
        for (int j = 0; j < 4; ++j)
            xs4[threadIdx.x + 256 * j] = xg[threadIdx.x + 256 * j];
        ((float*)hb)[threadIdx.x] = 0.f;
    }

    // ---- per-lane weights (asm-pinned): unit u's 15 rows, cols 4c..4c+3.
    // Pre-scaled: r/z rows by -L2E (sigmoid via exp2), n rows by 2*L2E (tanh).
    v2f w0r[2], w0z[2], w0n[2];                          // L0 hh
    v2f w1r[2], w1z[2], w1n[2], v1r[2], v1z[2], v1n[2];  // L1 hh + ih
    v2f w2r[2], w2z[2], w2n[2], v2r[2], v2z[2], v2n[2];  // L2 hh + ih
#define LDW(dst, base, l, q, s)                                            \
    _Pragma("unroll") for (int m = 0; m < 2; ++m)                          \
        dst[m] = ldg2((base) + ((l) * 48 + (q) * 16 + u) * 16 + 4 * c + 2 * m) * (s);
    LDW(w0r, w_hh, 0, 0, -L2E) LDW(w0z, w_hh, 0, 1, -L2E) LDW(w0n, w_hh, 0, 2, 2.f * L2E)
    LDW(w1r, w_hh, 1, 0, -L2E) LDW(w1z, w_hh, 1, 1, -L2E) LDW(w1n, w_hh, 1, 2, 2.f * L2E)
    LDW(w2r, w_hh, 2, 0, -L2E) LDW(w2z, w_hh, 2, 1, -L2E) LDW(w2n, w_hh, 2, 2, 2.f * L2E)
    LDW(v1r, w_ih12, 0, 0, -L2E) LDW(v1z, w_ih12, 0, 1, -L2E) LDW(v1n, w_ih12, 0, 2, 2.f * L2E)
    LDW(v2r, w_ih12, 1, 0, -L2E) LDW(v2z, w_ih12, 1, 1, -L2E) LDW(v2n, w_ih12, 1, 2, 2.f * L2E)
#undef LDW

    // ---- biases: nonzero only on c==0 (counted once per quad sum)
    float b_r[3], b_z[3], b_nh[3], b_nx1, b_nx2;
#pragma unroll
    for (int l = 0; l < 3; ++l) {
        float vr = -(ldg1(b_ih + l * 48 + u) + ldg1(b_hh + l * 48 + u)) * L2E;
        float vz = -(ldg1(b_ih + l * 48 + 16 + u) + ldg1(b_hh + l * 48 + 16 + u)) * L2E;
        float vn = ldg1(b_hh + l * 48 + 32 + u) * (2.f * L2E);
        b_r[l] = (c == 0) ? vr : 0.f;
        b_z[l] = (c == 0) ? vz : 0.f;
        b_nh[l] = (c == 0) ? vn : 0.f;
    }
    b_nx1 = (c == 0) ? ldg1(b_ih + 1 * 48 + 32 + u) * (2.f * L2E) : 0.f;
    b_nx2 = (c == 0) ? ldg1(b_ih + 2 * 48 + 32 + u) * (2.f * L2E) : 0.f;
    const float bnx0 = ldg1(b_ih + 32 + u) * (2.f * L2E);  // all lanes
    const float wxr = ldg1(w_ih0 + u) * -L2E;
    const float wxz = ldg1(w_ih0 + 16 + u) * -L2E;
    const float wxn = ldg1(w_ih0 + 32 + u) * (2.f * L2E);
    const float wx01 = (c == 0) ? wxr : ((c == 1) ? wxz : 0.f);

    __syncthreads();  // xs + hb ready

    // ---- state: 4-col slices of h0/h1/h2 + own role h (c0:h0[u],c1:h1[u],c2:h2[u])
    v2f h0s[2] = {{0.f, 0.f}, {0.f, 0.f}};
    v2f h1s[2] = {{0.f, 0.f}, {0.f, 0.f}};
    v2f h2s[2] = {{0.f, 0.f}, {0.f, 0.f}};
    float hown = 0.f;

    const float* xrow = &xs[slot][0];
    float* hbw = &hb[slot][c][u];          // role write (c3 -> dummy row)
    const float* hbr0 = &hb[slot][0][4 * c];
    const float* hbr1 = &hb[slot][1][4 * c];
    const float* hbr2 = &hb[slot][2][4 * c];

    // One diagonal iteration: L0 at t0, L1 at t0-1, L2 at t0-2 (independent).
    // Gate block = R5's HW-proven scheme: 3 pair-role sigmoid streams
    // (even lanes sigma(r), odd lanes sigma(z); dpp xor1 exchanges partner)
    // + local cndmask selects for the per-lane-layer tanh/update.
    auto step = [&](bool F0, bool F1, bool F2, float xt) {
        float sr0 = 0.f, sz0 = 0.f, snh0 = 0.f;
        float sr1 = 0.f, sz1 = 0.f, snh1 = 0.f, snx1 = 0.f;
        float sr2 = 0.f, sz2 = 0.f, snh2 = 0.f, snx2 = 0.f;
        if (F0) {
            sr0 = q4sumb(CH2(w0r, h0s), b_r[0]);
            sz0 = q4sumb(CH2(w0z, h0s), b_z[0]);
            snh0 = q4sumb(CH2(w0n, h0s), b_nh[0]);
        }
        if (F1) {
            sr1 = q4sumb(CH4(w1r, h1s, v1r, h0s), b_r[1]);
            sz1 = q4sumb(CH4(w1z, h1s, v1z, h0s), b_z[1]);
            snh1 = q4sumb(CH2(w1n, h1s), b_nh[1]);
            snx1 = q4sumb(CH2(v1n, h0s), b_nx1);
        }
        if (F2) {
            sr2 = q4sumb(CH4(w2r, h2s, v2r, h1s), b_r[2]);
            sz2 = q4sumb(CH4(w2z, h2s, v2z, h1s), b_z[2]);
            snh2 = q4sumb(CH2(w2n, h2s), b_nh[2]);
            snx2 = q4sumb(CH2(v2n, h1s), b_nx2);
        }
        // sigmoid streams (x folded into L0's on lanes c0/c1)
        float v0 = fmaf(wx01, xt, codd ? sz0 : sr0);
        float sg0 = rcpf_(1.f + ex2(v0));    // even: s(r0), odd: s(z0)
        float ot0 = dppf<0xB1>(sg0);         // partner's value
        float v1 = codd ? sz1 : sr1;
        float sg1 = rcpf_(1.f + ex2(v1));
        float ot1 = dppf<0xB1>(sg1);
        float v2_ = codd ? sz2 : sr2;
        float sg2 = rcpf_(1.f + ex2(v2_));
        float ot2 = dppf<0xB1>(sg2);
        // local selects: lane role c handles layer c (c3 = don't care)
        float rsel = g1m ? ot1 : (g2m ? sg2 : sg0);
        float zsel = g1m ? sg1 : (g2m ? ot2 : ot0);
        float ahs = g1m ? snh1 : (g2m ? snh2 : snh0);
        float axs = g1m ? snx1 : (g2m ? snx2 : fmaf(wxn, xt, bnx0));
        float ut = fmaf(rsel, ahs, axs);
        float n = fmaf(-2.f, rcpf_(ex2(ut) + 1.f), 1.f);
        float hn = fmaf(zsel, hown - n, n);
        bool act = g1m ? F1 : (g2m ? F2 : (g3m ? false : F0));
        hown = act ? hn : hown;
        *hbw = hown;  // 64 distinct LDS dwords: 2 lanes/bank = free
        // readback fresh slices (same-wave DS ops are program-ordered)
        v4f tv;
        tv = *(const v4f*)hbr0;
        h0s[0] = __builtin_shufflevector(tv, tv, 0, 1);
        h0s[1] = __builtin_shufflevector(tv, tv, 2, 3);
        tv = *(const v4f*)hbr1;
        h1s[0] = __builtin_shufflevector(tv, tv, 0, 1);
        h1s[1] = __builtin_shufflevector(tv, tv, 2, 3);
        tv = *(const v4f*)hbr2;
        h2s[0] = __builtin_shufflevector(tv, tv, 0, 1);
        h2s[1] = __builtin_shufflevector(tv, tv, 2, 3);
    };

    // ---- diagonal schedule with x prefetched one iteration ahead
    v2f xc = *(const v2f*)&xrow[0];
    step(true, false, false, xc.x);   // t0 = 0
    step(true, true, false, xc.y);    // t0 = 1
    v2f xn = *(const v2f*)&xrow[2];
    for (int t0 = 2; t0 < TSTEPS; t0 += 2) {
        xc = xn;
        xn = *(const v2f*)&xrow[(t0 + 2) & (TSTEPS - 1)];
        step(true, true, true, xc.x);
        step(true, true, true, xc.y);
    }
    step(false, true, true, 0.f);     // drain L1, L2
    step(false, false, true, 0.f);    // drain L2

    // ---- head on h2(1023) (in hb[slot][2][*])
    if (lane < 5) {
        float acc = fc_b[lane];
#pragma unroll
        for (int j = 0; j < 16; ++j)
            acc = fmaf(fc_w[lane * 16 + j], hb[slot][2][j], acc);
        out[seq * 5 + lane] = acc;
    }
}

extern "C" void kernel_launch(void* const* d_in, const int* in_sizes, int n_in,
                              void* d_out, int out_size, void* d_ws, size_t ws_size,
                              hipStream_t stream) {
    const float* x      = (const float*)d_in[0];
    const float* w_ih0  = (const float*)d_in[1];
    const float* w_ih12 = (const float*)d_in[2];
    const float* w_hh   = (const float*)d_in[3];
    const float* b_ih   = (const float*)d_in[4];
    const float* b_hh   = (const float*)d_in[5];
    const float* fc_w   = (const float*)d_in[6];
    const float* fc_b   = (const float*)d_in[7];
    float* out = (float*)d_out;

    // 4096 seqs x 64 lanes = 262144 threads = 4096 waves = 4 waves/SIMD
    gru3_r11<<<1024, 256, 0, stream>>>(
        x, w_ih0, w_ih12, w_hh, b_ih, b_hh, fc_w, fc_b, out);
}

// Round 12
// 539.148 us; speedup vs baseline: 1.5479x; 1.5479x over previous
//
#include <hip/hip_runtime.h>
#include <stdint.h>

#define TSTEPS 1024
#define L2E 1.4426950408889634f

typedef float v2f __attribute__((ext_vector_type(2)));
typedef float v4f __attribute__((ext_vector_type(4)));

__device__ __forceinline__ float rcpf_(float v) { return __builtin_amdgcn_rcpf(v); }
__device__ __forceinline__ float ex2(float v) { return __builtin_amdgcn_exp2f(v); }
#define PKFMA(a, b, c) __builtin_elementwise_fma((a), (b), (c))

// quad_perm [1,0,3,2]: exchange with lane^1 — pure VALU (HW-proven ctrl)
__device__ __forceinline__ float dpp_x1(float v) {
    return __int_as_float(__builtin_amdgcn_update_dpp(
        0, __float_as_int(v), 0xB1, 0xF, 0xF, true));
}
// total of a v2f partial across the lane pair (16 columns)
__device__ __forceinline__ float pairsum(v2f a) {
    float s = a.x + a.y;
    return s + dpp_x1(s);
}

// Opaque loads: value is asm-produced -> cannot be rematerialized as a load.
__device__ __forceinline__ v2f ldg2(const float* p) {
    v2f r; uint64_t a = (uint64_t)p;
    asm volatile("global_load_dwordx2 %0, %1, off\n\ts_waitcnt vmcnt(0)"
                 : "=v"(r) : "v"(a));
    return r;
}
__device__ __forceinline__ float ldg1(const float* p) {
    float r; uint64_t a = (uint64_t)p;
    asm volatile("global_load_dword %0, %1, off\n\ts_waitcnt vmcnt(0)"
                 : "=v"(r) : "v"(a));
    return r;
}

// 4-term and 8-term pk-FMA dot chains
#define CH4(W, H, SEED) \
    PKFMA(W[3], H[3], PKFMA(W[2], H[2], PKFMA(W[1], H[1], PKFMA(W[0], H[0], (SEED)))))
#define CH8(Wa, Ha, Wb, Hb, SEED) CH4(Wa, Ha, CH4(Wb, Hb, (SEED)))

// waves_per_eu(2,2): residency is grid-capped at 2 waves/SIMD anyway, so tell
// the RA to budget registers for exactly 2 (256 arch VGPRs) — otherwise it
// optimizes for phantom extra occupancy and parks the pinned weights in AGPRs,
// paying accvgpr shuffles in the hot loop.
__global__ __launch_bounds__(256, 2)
__attribute__((amdgpu_waves_per_eu(2, 2)))
void gru3_wpe(
    const float* __restrict__ x,      // [4096,1024,1]
    const float* __restrict__ w_ih0,  // [48,1]
    const float* __restrict__ w_ih12, // [2,48,16]
    const float* __restrict__ w_hh,   // [3,48,16]
    const float* __restrict__ b_ih,   // [3,48]
    const float* __restrict__ b_hh,   // [3,48]
    const float* __restrict__ fc_w,   // [5,16]
    const float* __restrict__ fc_b,   // [5]
    float* __restrict__ out)          // [4096,5]
{
    __shared__ float xs[8][TSTEPS];  // 32 KB
    __shared__ float hb[8][4][16];   // [grp][layer 0..2 + pad][unit]

    const int l31 = threadIdx.x & 31;  // lane within seq group
    const int grp = threadIdx.x >> 5;  // seq slot in block (0..7)
    const int u = l31 >> 1;            // hidden unit (0..15)
    const int c = l31 & 1;             // column half / role; partner = lane^1
    const int c8 = c * 8;
    const int seq = blockIdx.x * 8 + grp;

    // ---- stage x (coalesced float4) + zero h buffers
    {
        const float4* xg = (const float4*)(x + (size_t)blockIdx.x * 8 * TSTEPS);
        float4* xs4 = (float4*)&xs[0][0];
#pragma unroll
        for (int j = 0; j < 8; ++j)
            xs4[threadIdx.x + 256 * j] = xg[threadIdx.x + 256 * j];
        ((float*)hb)[threadIdx.x] = 0.f;
        ((float*)hb)[256 + threadIdx.x] = 0.f;
    }

    // ---- weights (asm-pinned), pre-scaled: r/z rows by -L2E (sigmoid via
    // exp2), n rows by 2*L2E (tanh via exp2).
    const float qs[3] = {-L2E, -L2E, 2.f * L2E};
    v2f wh[3][3][4];  // [layer][gate r,z,n][col pair], cols c8..c8+7
    v2f wi[2][3][4];
#pragma unroll
    for (int l = 0; l < 3; ++l)
#pragma unroll
        for (int q = 0; q < 3; ++q)
#pragma unroll
            for (int m = 0; m < 4; ++m)
                wh[l][q][m] =
                    ldg2(w_hh + (l * 48 + q * 16 + u) * 16 + c8 + 2 * m) * qs[q];
#pragma unroll
    for (int l = 0; l < 2; ++l)
#pragma unroll
        for (int q = 0; q < 3; ++q)
#pragma unroll
            for (int m = 0; m < 4; ++m)
                wi[l][q][m] =
                    ldg2(w_ih12 + (l * 48 + q * 16 + u) * 16 + c8 + 2 * m) * qs[q];

    // ---- biases as accumulator seeds (contribute once: c=0 lane, .x half)
    v2f bir[3], biz[3], binh[3], binx[2];
#pragma unroll
    for (int l = 0; l < 3; ++l) {
        float vr = -(ldg1(b_ih + l * 48 + u) + ldg1(b_hh + l * 48 + u)) * L2E;
        float vz = -(ldg1(b_ih + l * 48 + 16 + u) + ldg1(b_hh + l * 48 + 16 + u)) * L2E;
        float vn = ldg1(b_hh + l * 48 + 32 + u) * (2.f * L2E);
        bir[l] = (v2f){c ? 0.f : vr, 0.f};
        biz[l] = (v2f){c ? 0.f : vz, 0.f};
        binh[l] = (v2f){c ? 0.f : vn, 0.f};
    }
#pragma unroll
    for (int l = 0; l < 2; ++l) {
        float vx = ldg1(b_ih + (l + 1) * 48 + 32 + u) * (2.f * L2E);
        binx[l] = (v2f){c ? 0.f : vx, 0.f};
    }
    const float bnx0 = ldg1(b_ih + 32 + u) * (2.f * L2E);
    const float wxr = ldg1(w_ih0 + u) * -L2E;
    const float wxz = ldg1(w_ih0 + 16 + u) * -L2E;
    const float wxn = ldg1(w_ih0 + 32 + u) * (2.f * L2E);

    __syncthreads();  // xs + hb ready

    // ---- state: per-lane col slices + role-packed own h (c=0: h0[u], c=1: h1[u])
    v2f h0s[4], h1s[4], h2s[4];
#pragma unroll
    for (int m = 0; m < 4; ++m) {
        h0s[m] = (v2f){0.f, 0.f};
        h1s[m] = (v2f){0.f, 0.f};
        h2s[m] = (v2f){0.f, 0.f};
    }
    float h01o = 0.f;  // own h: layer c, unit u
    float h2o = 0.f;   // own h2[u] (both pair lanes)

    const float* xrow = &xs[grp][0];
    float* hw01 = &hb[grp][c][u];   // role write: c=0 -> h0 row, c=1 -> h1 row
    float* hw2 = &hb[grp][2][u];
    const float* hr0 = &hb[grp][0][c8];
    const float* hr1 = &hb[grp][1][c8];
    const float* hr2 = &hb[grp][2][c8];

#define RD4(dst, p)                                                       \
    do {                                                                  \
        v4f ta = *(const v4f*)(p);                                        \
        v4f tb = *(const v4f*)((p) + 4);                                  \
        dst[0] = __builtin_shufflevector(ta, ta, 0, 1);                   \
        dst[1] = __builtin_shufflevector(ta, ta, 2, 3);                   \
        dst[2] = __builtin_shufflevector(tb, tb, 0, 1);                   \
        dst[3] = __builtin_shufflevector(tb, tb, 2, 3);                   \
    } while (0)

    // One diagonal iteration: L0 at t0, L1 at t0-1, L2 at t0-2 (independent).
    // Sigmoid passes pair-split (c=0: sigma(r), c=1: sigma(z), DPP swap).
    // L0/L1 tanh+update packed: c=0 runs L0's n-gate + h0 update, c=1 runs L1's.
    auto step = [&](bool F0, bool F1, bool F2, float xt) {
        float sg0 = 0.f, og0 = 0.f, sg1 = 0.f, og1 = 0.f;
        float snh0 = 0.f, snx0 = 0.f, snh1 = 0.f, snx1 = 0.f;
        if (F0) {
            float sr = fmaf(wxr, xt, pairsum(CH4(wh[0][0], h0s, bir[0])));
            float sz = fmaf(wxz, xt, pairsum(CH4(wh[0][1], h0s, biz[0])));
            float p = c ? sz : sr;
            sg0 = rcpf_(1.f + ex2(p));   // c=0: r0, c=1: z0
            og0 = dpp_x1(sg0);           // c=0: z0, c=1: r0
            snh0 = pairsum(CH4(wh[0][2], h0s, binh[0]));
            snx0 = fmaf(wxn, xt, bnx0);
        }
        if (F1) {
            float sr = pairsum(CH8(wh[1][0], h1s, wi[0][0], h0s, bir[1]));
            float sz = pairsum(CH8(wh[1][1], h1s, wi[0][1], h0s, biz[1]));
            float p = c ? sz : sr;
            sg1 = rcpf_(1.f + ex2(p));   // c=0: r1, c=1: z1
            og1 = dpp_x1(sg1);           // c=0: z1, c=1: r1
            snh1 = pairsum(CH4(wh[1][2], h1s, binh[1]));
            snx1 = pairsum(CH4(wi[0][2], h0s, binx[0]));
        }
        if (F0 || F1) {
            // packed n-gate: lane role c picks its layer
            float rsel = c ? og1 : sg0;   // r_{Lc}
            float zsel = c ? sg1 : og0;   // z_{Lc}
            float snh = c ? snh1 : snh0;
            float snx = c ? snx1 : snx0;
            float ut = fmaf(rsel, snh, snx);
            float n = fmaf(-2.f, rcpf_(ex2(ut) + 1.f), 1.f);
            float hn = fmaf(zsel, h01o - n, n);
            bool act = c ? F1 : F0;       // compile-time folds in steady state
            h01o = act ? hn : h01o;
        }
        *hw01 = h01o;  // c=0 writes h0 row, c=1 writes h1 row (one ds_write)
        if (F2) {
            float sr = pairsum(CH8(wh[2][0], h2s, wi[1][0], h1s, bir[2]));
            float sz = pairsum(CH8(wh[2][1], h2s, wi[1][1], h1s, biz[2]));
            float p = c ? sz : sr;
            float sg = rcpf_(1.f + ex2(p));
            float og = dpp_x1(sg);
            float r2 = c ? og : sg;
            float z2 = c ? sg : og;
            float snh = pairsum(CH4(wh[2][2], h2s, binh[2]));
            float snx = pairsum(CH4(wi[1][2], h1s, binx[1]));
            float ut = fmaf(r2, snh, snx);
            float n = fmaf(-2.f, rcpf_(ex2(ut) + 1.f), 1.f);
            h2o = fmaf(z2, h2o - n, n);
        }
        *hw2 = h2o;
        // readback fresh slices (same-wave DS ops are program-ordered)
        RD4(h0s, hr0);
        RD4(h1s, hr1);
        RD4(h2s, hr2);
    };

    // ---- diagonal schedule with x prefetched one iteration ahead
    v2f xc = *(const v2f*)&xrow[0];
    step(true, false, false, xc.x);   // t0 = 0
    step(true, true, false, xc.y);    // t0 = 1
    v2f xn = *(const v2f*)&xrow[2];
    for (int t0 = 2; t0 < TSTEPS; t0 += 2) {
        xc = xn;
        xn = *(const v2f*)&xrow[(t0 + 2) & (TSTEPS - 1)];  // next-iter prefetch
        step(true, true, true, xc.x);
        step(true, true, true, xc.y);
    }
    step(false, true, true, 0.f);     // drain L1, L2
    step(false, false, true, 0.f);    // drain L2

    // ---- head on h2(1023) (in hb[grp][2][*])
    if (l31 < 5) {
        float acc = fc_b[l31];
#pragma unroll
        for (int j = 0; j < 16; ++j)
            acc = fmaf(fc_w[l31 * 16 + j], hb[grp][2][j], acc);
        out[seq * 5 + l31] = acc;
    }
#undef RD4
}

extern "C" void kernel_launch(void* const* d_in, const int* in_sizes, int n_in,
                              void* d_out, int out_size, void* d_ws, size_t ws_size,
                              hipStream_t stream) {
    const float* x      = (const float*)d_in[0];
    const float* w_ih0  = (const float*)d_in[1];
    const float* w_ih12 = (const float*)d_in[2];
    const float* w_hh   = (const float*)d_in[3];
    const float* b_ih   = (const float*)d_in[4];
    const float* b_hh   = (const float*)d_in[5];
    const float* fc_w   = (const float*)d_in[6];
    const float* fc_b   = (const float*)d_in[7];
    float* out = (float*)d_out;

    // 4096 seqs x 32 lanes = 131072 threads = 2048 waves = 2 waves/SIMD
    gru3_wpe<<<512, 256, 0, stream>>>(
        x, w_ih0, w_ih12, w_hh, b_ih, b_hh, fc_w, fc_b, out);
}

// Round 13
// 513.220 us; speedup vs baseline: 1.6261x; 1.0505x over previous
//
#include <hip/hip_runtime.h>
#include <stdint.h>

#define TSTEPS 1024
#define L2E 1.4426950408889634f
#define XPITCH 1028  // padded x row (dwords): breaks 4-way bank alias, 16B-aligned

typedef float v2f __attribute__((ext_vector_type(2)));
typedef float v4f __attribute__((ext_vector_type(4)));

__device__ __forceinline__ float rcpf_(float v) { return __builtin_amdgcn_rcpf(v); }
__device__ __forceinline__ float ex2(float v) { return __builtin_amdgcn_exp2f(v); }
#define PKFMA(a, b, c) __builtin_elementwise_fma((a), (b), (c))

// Opaque loads: value is asm-produced -> cannot be rematerialized as a load.
__device__ __forceinline__ v2f ldg2(const float* p) {
    v2f r; uint64_t a = (uint64_t)p;
    asm volatile("global_load_dwordx2 %0, %1, off\n\ts_waitcnt vmcnt(0)"
                 : "=v"(r) : "v"(a));
    return r;
}
__device__ __forceinline__ float ldg1(const float* p) {
    float r; uint64_t a = (uint64_t)p;
    asm volatile("global_load_dword %0, %1, off\n\ts_waitcnt vmcnt(0)"
                 : "=v"(r) : "v"(a));
    return r;
}

// read 16 consecutive LDS floats (one h vector) into 8 v2f (4x ds_read_b128)
#define RDH(dst, p)                                                        \
    do {                                                                   \
        v4f a0 = *(const v4f*)(p);                                         \
        v4f a1 = *(const v4f*)((p) + 4);                                   \
        v4f a2 = *(const v4f*)((p) + 8);                                   \
        v4f a3 = *(const v4f*)((p) + 12);                                  \
        dst[0] = __builtin_shufflevector(a0, a0, 0, 1);                    \
        dst[1] = __builtin_shufflevector(a0, a0, 2, 3);                    \
        dst[2] = __builtin_shufflevector(a1, a1, 0, 1);                    \
        dst[3] = __builtin_shufflevector(a1, a1, 2, 3);                    \
        dst[4] = __builtin_shufflevector(a2, a2, 0, 1);                    \
        dst[5] = __builtin_shufflevector(a2, a2, 2, 3);                    \
        dst[6] = __builtin_shufflevector(a3, a3, 0, 1);                    \
        dst[7] = __builtin_shufflevector(a3, a3, 2, 3);                    \
    } while (0)

// full-row dots (lane-local, no cross-lane reduce): 8 and 16 v2f chains
#define DOT8(w, h, seed)                                                   \
    ({                                                                     \
        v2f _a = PKFMA(w[0], h[0], (seed));                                \
        _a = PKFMA(w[1], h[1], _a); _a = PKFMA(w[2], h[2], _a);            \
        _a = PKFMA(w[3], h[3], _a); _a = PKFMA(w[4], h[4], _a);            \
        _a = PKFMA(w[5], h[5], _a); _a = PKFMA(w[6], h[6], _a);            \
        _a = PKFMA(w[7], h[7], _a);                                        \
        _a.x + _a.y;                                                       \
    })
#define DOT16(wa, ha, wb, hb, seed)                                        \
    ({                                                                     \
        v2f _a = PKFMA(wa[0], ha[0], (seed));                              \
        _a = PKFMA(wa[1], ha[1], _a); _a = PKFMA(wa[2], ha[2], _a);        \
        _a = PKFMA(wa[3], ha[3], _a); _a = PKFMA(wa[4], ha[4], _a);        \
        _a = PKFMA(wa[5], ha[5], _a); _a = PKFMA(wa[6], ha[6], _a);        \
        _a = PKFMA(wa[7], ha[7], _a);                                      \
        _a = PKFMA(wb[0], hb[0], _a); _a = PKFMA(wb[1], hb[1], _a);        \
        _a = PKFMA(wb[2], hb[2], _a); _a = PKFMA(wb[3], hb[3], _a);        \
        _a = PKFMA(wb[4], hb[4], _a); _a = PKFMA(wb[5], hb[5], _a);        \
        _a = PKFMA(wb[6], hb[6], _a); _a = PKFMA(wb[7], hb[7], _a);        \
        _a.x + _a.y;                                                       \
    })

// 12 waves/block: waves 0-3 = layer0, 4-7 = layer1, 8-11 = layer2.
// Each wave: 4 seqs x 16 lanes (lane = hidden unit, FULL weight row -> no
// cross-lane reduction). Layers exchange h via double-buffered LDS; one
// __syncthreads per timestep; diagonal schedule across roles. Separate
// per-role loops keep the three weight register sets from being live
// simultaneously (union would blow the 3-waves/SIMD VGPR budget).
__global__ __launch_bounds__(768, 3)
__attribute__((amdgpu_waves_per_eu(3, 3)))
void gru3_ws(
    const float* __restrict__ x,      // [4096,1024,1]
    const float* __restrict__ w_ih0,  // [48,1]
    const float* __restrict__ w_ih12, // [2,48,16]
    const float* __restrict__ w_hh,   // [3,48,16]
    const float* __restrict__ b_ih,   // [3,48]
    const float* __restrict__ b_hh,   // [3,48]
    const float* __restrict__ fc_w,   // [5,16]
    const float* __restrict__ fc_b,   // [5]
    float* __restrict__ out)          // [4096,5]
{
    __shared__ float xs[16 * XPITCH];       // 65792 B padded x rows
    __shared__ float hbuf[2][16][3][16];    // 6144 B [buf][seq][layer][unit]

    const int tid = threadIdx.x;
    const int wave = tid >> 6;
    const int role = wave >> 2;        // 0,1,2 = layer
    const int lane = tid & 63;
    const int s = lane >> 4;           // seq within wave (0..3)
    const int u = lane & 15;           // hidden unit
    const int lseq = (wave & 3) * 4 + s;
    const int seq = blockIdx.x * 16 + lseq;

    // ---- stage x (coalesced float4, padded rows) + zero h buffers
    {
        const float4* xg = (const float4*)(x + (size_t)blockIdx.x * 16 * TSTEPS);
#pragma unroll
        for (int j = 0; j < 6; ++j) {
            int idx = tid + 768 * j;
            if (idx < 4096) {
                float4 v = xg[idx];
                *(float4*)&xs[(idx >> 8) * XPITCH + (idx & 255) * 4] = v;
            }
        }
        ((float*)hbuf)[tid] = 0.f;
        if (tid < 1536 - 768) ((float*)hbuf)[768 + tid] = 0.f;
    }
    __syncthreads();

    if (role == 0) {
        // ---- layer 0: input dim 1 (x-side scalar), hh rows of w_hh[0]
        v2f wr[8], wz[8], wn[8];
#pragma unroll
        for (int m = 0; m < 8; ++m) {
            wr[m] = ldg2(w_hh + (0 * 48 + u) * 16 + 2 * m) * -L2E;
            wz[m] = ldg2(w_hh + (0 * 48 + 16 + u) * 16 + 2 * m) * -L2E;
            wn[m] = ldg2(w_hh + (0 * 48 + 32 + u) * 16 + 2 * m) * (2.f * L2E);
        }
        const float wxr = ldg1(w_ih0 + u) * -L2E;
        const float wxz = ldg1(w_ih0 + 16 + u) * -L2E;
        const float wxn = ldg1(w_ih0 + 32 + u) * (2.f * L2E);
        const v2f sbr = {-(ldg1(b_ih + u) + ldg1(b_hh + u)) * L2E, 0.f};
        const v2f sbz = {-(ldg1(b_ih + 16 + u) + ldg1(b_hh + 16 + u)) * L2E, 0.f};
        const v2f sbn = {ldg1(b_hh + 32 + u) * (2.f * L2E), 0.f};
        const float bnx = ldg1(b_ih + 32 + u) * (2.f * L2E);
        const float* xrow = &xs[lseq * XPITCH];
        float* wb0 = &hbuf[0][lseq][0][0];
        float* wb1 = &hbuf[1][lseq][0][0];
        float hown = 0.f;
#pragma unroll 2
        for (int k = 0; k < 1026; ++k) {
            if (k < 1024) {  // compute t = k
                const float* rb = (k & 1) ? wb0 : wb1;  // prev buffer
                v2f hp[8];
                RDH(hp, rb);
                float xt = xrow[k];
                float sr = fmaf(wxr, xt, DOT8(wr, hp, sbr));
                float sz = fmaf(wxz, xt, DOT8(wz, hp, sbz));
                float snh = DOT8(wn, hp, sbn);
                float r = rcpf_(1.f + ex2(sr));
                float z = rcpf_(1.f + ex2(sz));
                float ut = fmaf(r, snh, fmaf(wxn, xt, bnx));
                float n = fmaf(-2.f, rcpf_(ex2(ut) + 1.f), 1.f);
                hown = fmaf(z, hown - n, n);
                ((k & 1) ? wb1 : wb0)[u] = hown;
            }
            __syncthreads();
        }
    } else if (role == 1) {
        // ---- layer 1: hh rows of w_hh[1], ih rows of w_ih12[0]
        v2f wr[8], wz[8], wn[8], vr[8], vz[8], vn[8];
#pragma unroll
        for (int m = 0; m < 8; ++m) {
            wr[m] = ldg2(w_hh + (48 + u) * 16 + 2 * m) * -L2E;
            wz[m] = ldg2(w_hh + (48 + 16 + u) * 16 + 2 * m) * -L2E;
            wn[m] = ldg2(w_hh + (48 + 32 + u) * 16 + 2 * m) * (2.f * L2E);
            vr[m] = ldg2(w_ih12 + (u) * 16 + 2 * m) * -L2E;
            vz[m] = ldg2(w_ih12 + (16 + u) * 16 + 2 * m) * -L2E;
            vn[m] = ldg2(w_ih12 + (32 + u) * 16 + 2 * m) * (2.f * L2E);
        }
        const v2f sbr = {-(ldg1(b_ih + 48 + u) + ldg1(b_hh + 48 + u)) * L2E, 0.f};
        const v2f sbz = {-(ldg1(b_ih + 64 + u) + ldg1(b_hh + 64 + u)) * L2E, 0.f};
        const v2f sbn = {ldg1(b_hh + 80 + u) * (2.f * L2E), 0.f};
        const v2f sbx = {ldg1(b_ih + 80 + u) * (2.f * L2E), 0.f};
        float* base0 = &hbuf[0][lseq][0][0];
        float* base1 = &hbuf[1][lseq][0][0];
        float hown = 0.f;
#pragma unroll 2
        for (int k = 0; k < 1026; ++k) {
            if (k >= 1 && k <= 1024) {  // compute t = k-1
                const float* rb = (k & 1) ? base0 : base1;
                v2f hin[8], hp[8];
                RDH(hin, rb);        // h0(k-1) = layer-0 input at t
                RDH(hp, rb + 16);    // h1(k-2) = own recurrent
                float sr = DOT16(wr, hp, vr, hin, sbr);
                float sz = DOT16(wz, hp, vz, hin, sbz);
                float snh = DOT8(wn, hp, sbn);
                float snx = DOT8(vn, hin, sbx);
                float r = rcpf_(1.f + ex2(sr));
                float z = rcpf_(1.f + ex2(sz));
                float ut = fmaf(r, snh, snx);
                float n = fmaf(-2.f, rcpf_(ex2(ut) + 1.f), 1.f);
                hown = fmaf(z, hown - n, n);
                ((k & 1) ? base1 : base0)[16 + u] = hown;
            }
            __syncthreads();
        }
    } else {
        // ---- layer 2: hh rows of w_hh[2], ih rows of w_ih12[1]
        v2f wr[8], wz[8], wn[8], vr[8], vz[8], vn[8];
#pragma unroll
        for (int m = 0; m < 8; ++m) {
            wr[m] = ldg2(w_hh + (96 + u) * 16 + 2 * m) * -L2E;
            wz[m] = ldg2(w_hh + (96 + 16 + u) * 16 + 2 * m) * -L2E;
            wn[m] = ldg2(w_hh + (96 + 32 + u) * 16 + 2 * m) * (2.f * L2E);
            vr[m] = ldg2(w_ih12 + (48 + u) * 16 + 2 * m) * -L2E;
            vz[m] = ldg2(w_ih12 + (48 + 16 + u) * 16 + 2 * m) * -L2E;
            vn[m] = ldg2(w_ih12 + (48 + 32 + u) * 16 + 2 * m) * (2.f * L2E);
        }
        const v2f sbr = {-(ldg1(b_ih + 96 + u) + ldg1(b_hh + 96 + u)) * L2E, 0.f};
        const v2f sbz = {-(ldg1(b_ih + 112 + u) + ldg1(b_hh + 112 + u)) * L2E, 0.f};
        const v2f sbn = {ldg1(b_hh + 128 + u) * (2.f * L2E), 0.f};
        const v2f sbx = {ldg1(b_ih + 128 + u) * (2.f * L2E), 0.f};
        float* base0 = &hbuf[0][lseq][0][0];
        float* base1 = &hbuf[1][lseq][0][0];
        float hown = 0.f;
#pragma unroll 2
        for (int k = 0; k < 1026; ++k) {
            if (k >= 2) {  // compute t = k-2 (k<=1025 always)
                const float* rb = (k & 1) ? base0 : base1;
                v2f hin[8], hp[8];
                RDH(hin, rb + 16);   // h1(k-2) = layer-1 input at t
                RDH(hp, rb + 32);    // h2(k-3) = own recurrent
                float sr = DOT16(wr, hp, vr, hin, sbr);
                float sz = DOT16(wz, hp, vz, hin, sbz);
                float snh = DOT8(wn, hp, sbn);
                float snx = DOT8(vn, hin, sbx);
                float r = rcpf_(1.f + ex2(sr));
                float z = rcpf_(1.f + ex2(sz));
                float ut = fmaf(r, snh, snx);
                float n = fmaf(-2.f, rcpf_(ex2(ut) + 1.f), 1.f);
                hown = fmaf(z, hown - n, n);
                ((k & 1) ? base1 : base0)[32 + u] = hown;
            }
            __syncthreads();
        }
        // ---- head: h2(1023) was written at k=1025 -> buf[1]; same-wave reads
        if (u < 5) {
            const float* h2f = &hbuf[1][lseq][2][0];
            float acc = fc_b[u];
#pragma unroll
            for (int j = 0; j < 16; ++j)
                acc = fmaf(fc_w[u * 16 + j], h2f[j], acc);
            out[seq * 5 + u] = acc;
        }
    }
}

extern "C" void kernel_launch(void* const* d_in, const int* in_sizes, int n_in,
                              void* d_out, int out_size, void* d_ws, size_t ws_size,
                              hipStream_t stream) {
    const float* x      = (const float*)d_in[0];
    const float* w_ih0  = (const float*)d_in[1];
    const float* w_ih12 = (const float*)d_in[2];
    const float* w_hh   = (const float*)d_in[3];
    const float* b_ih   = (const float*)d_in[4];
    const float* b_hh   = (const float*)d_in[5];
    const float* fc_w   = (const float*)d_in[6];
    const float* fc_b   = (const float*)d_in[7];
    float* out = (float*)d_out;

    // 256 blocks x 768 threads: 16 seqs/block, 12 waves (4 quads x 3 layer
    // roles) -> 1 block/CU, 3 waves/SIMD.
    gru3_ws<<<256, 768, 0, stream>>>(
        x, w_ih0, w_ih12, w_hh, b_ih, b_hh, fc_w, fc_b, out);
}

// Round 14
// 492.325 us; speedup vs baseline: 1.6951x; 1.0424x over previous
//
#include <hip/hip_runtime.h>
#include <stdint.h>

#define TSTEPS 1024
#define S 4          // timesteps per super-iter (layer skew)
#define NK 258       // 1024/S + 2 pipeline-drain super-iters
#define L2E 1.4426950408889634f
#define XPITCH 1028  // padded x row (dwords): bank-spread rows, 16B-aligned

typedef float v2f __attribute__((ext_vector_type(2)));
typedef float v4f __attribute__((ext_vector_type(4)));

__device__ __forceinline__ float rcpf_(float v) { return __builtin_amdgcn_rcpf(v); }
__device__ __forceinline__ float ex2(float v) { return __builtin_amdgcn_exp2f(v); }
#define PKFMA(a, b, c) __builtin_elementwise_fma((a), (b), (c))

// Opaque loads: value is asm-produced -> cannot be rematerialized as a load.
__device__ __forceinline__ v2f ldg2(const float* p) {
    v2f r; uint64_t a = (uint64_t)p;
    asm volatile("global_load_dwordx2 %0, %1, off\n\ts_waitcnt vmcnt(0)"
                 : "=v"(r) : "v"(a));
    return r;
}
__device__ __forceinline__ float ldg1(const float* p) {
    float r; uint64_t a = (uint64_t)p;
    asm volatile("global_load_dword %0, %1, off\n\ts_waitcnt vmcnt(0)"
                 : "=v"(r) : "v"(a));
    return r;
}

// read 16 consecutive LDS floats (one h vector) into 8 v2f (4x ds_read_b128)
#define RDH(dst, p)                                                        \
    do {                                                                   \
        v4f a0 = *(const v4f*)(p);                                         \
        v4f a1 = *(const v4f*)((p) + 4);                                   \
        v4f a2 = *(const v4f*)((p) + 8);                                   \
        v4f a3 = *(const v4f*)((p) + 12);                                  \
        dst[0] = __builtin_shufflevector(a0, a0, 0, 1);                    \
        dst[1] = __builtin_shufflevector(a0, a0, 2, 3);                    \
        dst[2] = __builtin_shufflevector(a1, a1, 0, 1);                    \
        dst[3] = __builtin_shufflevector(a1, a1, 2, 3);                    \
        dst[4] = __builtin_shufflevector(a2, a2, 0, 1);                    \
        dst[5] = __builtin_shufflevector(a2, a2, 2, 3);                    \
        dst[6] = __builtin_shufflevector(a3, a3, 0, 1);                    \
        dst[7] = __builtin_shufflevector(a3, a3, 2, 3);                    \
    } while (0)

#define DOT8(w, h, seed)                                                   \
    ({                                                                     \
        v2f _a = PKFMA(w[0], h[0], (seed));                                \
        _a = PKFMA(w[1], h[1], _a); _a = PKFMA(w[2], h[2], _a);            \
        _a = PKFMA(w[3], h[3], _a); _a = PKFMA(w[4], h[4], _a);            \
        _a = PKFMA(w[5], h[5], _a); _a = PKFMA(w[6], h[6], _a);            \
        _a = PKFMA(w[7], h[7], _a);                                        \
        _a.x + _a.y;                                                       \
    })
#define DOT16(wa, ha, wb, hb, seed)                                        \
    ({                                                                     \
        v2f _a = PKFMA(wa[0], ha[0], (seed));                              \
        _a = PKFMA(wa[1], ha[1], _a); _a = PKFMA(wa[2], ha[2], _a);        \
        _a = PKFMA(wa[3], ha[3], _a); _a = PKFMA(wa[4], ha[4], _a);        \
        _a = PKFMA(wa[5], ha[5], _a); _a = PKFMA(wa[6], ha[6], _a);        \
        _a = PKFMA(wa[7], ha[7], _a);                                      \
        _a = PKFMA(wb[0], hb[0], _a); _a = PKFMA(wb[1], hb[1], _a);        \
        _a = PKFMA(wb[2], hb[2], _a); _a = PKFMA(wb[3], hb[3], _a);        \
        _a = PKFMA(wb[4], hb[4], _a); _a = PKFMA(wb[5], hb[5], _a);        \
        _a = PKFMA(wb[6], hb[6], _a); _a = PKFMA(wb[7], hb[7], _a);        \
        _a.x + _a.y;                                                       \
    })

// Block = 3 waves (one per layer) x 4 seqs. Layers skewed by S timesteps;
// cross-layer h handoff through double-buffered rings (buf = K&1), barrier
// once per super-iter. Own-layer recurrent reads are same-wave DS
// (program-ordered) and never wait on the barrier.
__global__ __launch_bounds__(192, 3)
__attribute__((amdgpu_waves_per_eu(3, 3)))
void gru3_sk(
    const float* __restrict__ x,      // [4096,1024,1]
    const float* __restrict__ w_ih0,  // [48,1]
    const float* __restrict__ w_ih12, // [2,48,16]
    const float* __restrict__ w_hh,   // [3,48,16]
    const float* __restrict__ b_ih,   // [3,48]
    const float* __restrict__ b_hh,   // [3,48]
    const float* __restrict__ fc_w,   // [5,16]
    const float* __restrict__ fc_b,   // [5]
    float* __restrict__ out)          // [4096,5]
{
    __shared__ float xs[4][XPITCH];          // 16448 B padded x rows
    __shared__ float hring[3][2][S][4][16];  // 6144 B [layer][buf][slot][seq][unit]
    __shared__ float h2f[4][16];             // head staging

    const int tid = threadIdx.x;
    const int role = tid >> 6;         // wave = layer
    const int lane = tid & 63;
    const int s = lane >> 4;           // seq within block (0..3)
    const int u = lane & 15;           // hidden unit
    const int seq = blockIdx.x * 4 + s;

    // ---- stage x (coalesced float4, padded rows) + zero rings
    {
        const float4* xg = (const float4*)(x + (size_t)blockIdx.x * 4 * TSTEPS);
#pragma unroll
        for (int j = 0; j < 6; ++j) {
            int idx = tid + 192 * j;
            if (idx < 1024) {
                float4 v = xg[idx];
                *(float4*)&xs[idx >> 8][(idx & 255) * 4] = v;
            }
        }
#pragma unroll
        for (int j = 0; j < 8; ++j)
            ((float*)hring)[tid + 192 * j] = 0.f;
    }
    __syncthreads();

    if (role == 0) {
        // ---- layer 0: t = K*S + j
        v2f wr[8], wz[8], wn[8];
#pragma unroll
        for (int m = 0; m < 8; ++m) {
            wr[m] = ldg2(w_hh + (u) * 16 + 2 * m) * -L2E;
            wz[m] = ldg2(w_hh + (16 + u) * 16 + 2 * m) * -L2E;
            wn[m] = ldg2(w_hh + (32 + u) * 16 + 2 * m) * (2.f * L2E);
        }
        const float wxr = ldg1(w_ih0 + u) * -L2E;
        const float wxz = ldg1(w_ih0 + 16 + u) * -L2E;
        const float wxn = ldg1(w_ih0 + 32 + u) * (2.f * L2E);
        const v2f sbr = {-(ldg1(b_ih + u) + ldg1(b_hh + u)) * L2E, 0.f};
        const v2f sbz = {-(ldg1(b_ih + 16 + u) + ldg1(b_hh + 16 + u)) * L2E, 0.f};
        const v2f sbn = {ldg1(b_hh + 32 + u) * (2.f * L2E), 0.f};
        const float bnx = ldg1(b_ih + 32 + u) * (2.f * L2E);
        float* cur = &hring[0][0][0][s][0];  // buf K&1 (slot stride 64 floats)
        float* prv = &hring[0][1][0][s][0];
        float hown = 0.f;
        for (int K = 0; K < NK; ++K) {
            if (K < 256) {
                v4f xq = *(const v4f*)&xs[s][K * S];
#pragma unroll
                for (int j = 0; j < S; ++j) {
                    const float* rb = (j == 0) ? (prv + (S - 1) * 64)
                                               : (cur + (j - 1) * 64);
                    v2f hp[8];
                    RDH(hp, rb);
                    float xt = xq[j];
                    float sr = fmaf(wxr, xt, DOT8(wr, hp, sbr));
                    float sz = fmaf(wxz, xt, DOT8(wz, hp, sbz));
                    float snh = DOT8(wn, hp, sbn);
                    float r = rcpf_(1.f + ex2(sr));
                    float z = rcpf_(1.f + ex2(sz));
                    float ut = fmaf(r, snh, fmaf(wxn, xt, bnx));
                    float n = fmaf(-2.f, rcpf_(ex2(ut) + 1.f), 1.f);
                    hown = fmaf(z, hown - n, n);
                    cur[j * 64 + u] = hown;
                }
            }
            __syncthreads();
            float* t_ = cur; cur = prv; prv = t_;
        }
    } else if (role == 1) {
        // ---- layer 1: t = (K-1)*S + j; input h0 from hring[0][(K-1)&1]
        v2f wr[8], wz[8], wn[8], vr[8], vz[8], vn[8];
#pragma unroll
        for (int m = 0; m < 8; ++m) {
            wr[m] = ldg2(w_hh + (48 + u) * 16 + 2 * m) * -L2E;
            wz[m] = ldg2(w_hh + (48 + 16 + u) * 16 + 2 * m) * -L2E;
            wn[m] = ldg2(w_hh + (48 + 32 + u) * 16 + 2 * m) * (2.f * L2E);
            vr[m] = ldg2(w_ih12 + (u) * 16 + 2 * m) * -L2E;
            vz[m] = ldg2(w_ih12 + (16 + u) * 16 + 2 * m) * -L2E;
            vn[m] = ldg2(w_ih12 + (32 + u) * 16 + 2 * m) * (2.f * L2E);
        }
        const v2f sbr = {-(ldg1(b_ih + 48 + u) + ldg1(b_hh + 48 + u)) * L2E, 0.f};
        const v2f sbz = {-(ldg1(b_ih + 64 + u) + ldg1(b_hh + 64 + u)) * L2E, 0.f};
        const v2f sbn = {ldg1(b_hh + 80 + u) * (2.f * L2E), 0.f};
        const v2f sbx = {ldg1(b_ih + 80 + u) * (2.f * L2E), 0.f};
        float* in0 = &hring[0][0][0][s][0];
        float* in1 = &hring[0][1][0][s][0];
        float* my0 = &hring[1][0][0][s][0];
        float* my1 = &hring[1][1][0][s][0];
        float* inp = in1;  // at K: in[(K-1)&1]; K=0 -> [1] (unused), swap->K=1:[0]
        float* mycur = my0; float* myprv = my1;
        float hown = 0.f;
        for (int K = 0; K < NK; ++K) {
            if (K >= 1 && K < 257) {
#pragma unroll
                for (int j = 0; j < S; ++j) {
                    const float* rin = inp + j * 64;
                    const float* rown = (j == 0) ? (myprv + (S - 1) * 64)
                                                 : (mycur + (j - 1) * 64);
                    v2f hin[8], hp[8];
                    RDH(hin, rin);
                    RDH(hp, rown);
                    float sr = DOT16(wr, hp, vr, hin, sbr);
                    float sz = DOT16(wz, hp, vz, hin, sbz);
                    float snh = DOT8(wn, hp, sbn);
                    float snx = DOT8(vn, hin, sbx);
                    float r = rcpf_(1.f + ex2(sr));
                    float z = rcpf_(1.f + ex2(sz));
                    float ut = fmaf(r, snh, snx);
                    float n = fmaf(-2.f, rcpf_(ex2(ut) + 1.f), 1.f);
                    hown = fmaf(z, hown - n, n);
                    mycur[j * 64 + u] = hown;
                }
            }
            __syncthreads();
            float* t_ = inp == in0 ? in1 : in0; inp = t_;
            t_ = mycur; mycur = myprv; myprv = t_;
        }
    } else {
        // ---- layer 2: t = (K-2)*S + j; input h1 from hring[1][(K-1)&1]
        v2f wr[8], wz[8], wn[8], vr[8], vz[8], vn[8];
#pragma unroll
        for (int m = 0; m < 8; ++m) {
            wr[m] = ldg2(w_hh + (96 + u) * 16 + 2 * m) * -L2E;
            wz[m] = ldg2(w_hh + (96 + 16 + u) * 16 + 2 * m) * -L2E;
            wn[m] = ldg2(w_hh + (96 + 32 + u) * 16 + 2 * m) * (2.f * L2E);
            vr[m] = ldg2(w_ih12 + (48 + u) * 16 + 2 * m) * -L2E;
            vz[m] = ldg2(w_ih12 + (48 + 16 + u) * 16 + 2 * m) * -L2E;
            vn[m] = ldg2(w_ih12 + (48 + 32 + u) * 16 + 2 * m) * (2.f * L2E);
        }
        const v2f sbr = {-(ldg1(b_ih + 96 + u) + ldg1(b_hh + 96 + u)) * L2E, 0.f};
        const v2f sbz = {-(ldg1(b_ih + 112 + u) + ldg1(b_hh + 112 + u)) * L2E, 0.f};
        const v2f sbn = {ldg1(b_hh + 128 + u) * (2.f * L2E), 0.f};
        const v2f sbx = {ldg1(b_ih + 128 + u) * (2.f * L2E), 0.f};
        float* in0 = &hring[1][0][0][s][0];
        float* in1 = &hring[1][1][0][s][0];
        float* my0 = &hring[2][0][0][s][0];
        float* my1 = &hring[2][1][0][s][0];
        float* inp = in1;
        float* mycur = my0; float* myprv = my1;
        float hown = 0.f;
        for (int K = 0; K < NK; ++K) {
            if (K >= 2) {
#pragma unroll
                for (int j = 0; j < S; ++j) {
                    const float* rin = inp + j * 64;
                    const float* rown = (j == 0) ? (myprv + (S - 1) * 64)
                                                 : (mycur + (j - 1) * 64);
                    v2f hin[8], hp[8];
                    RDH(hin, rin);
                    RDH(hp, rown);
                    float sr = DOT16(wr, hp, vr, hin, sbr);
                    float sz = DOT16(wz, hp, vz, hin, sbz);
                    float snh = DOT8(wn, hp, sbn);
                    float snx = DOT8(vn, hin, sbx);
                    float r = rcpf_(1.f + ex2(sr));
                    float z = rcpf_(1.f + ex2(sz));
                    float ut = fmaf(r, snh, snx);
                    float n = fmaf(-2.f, rcpf_(ex2(ut) + 1.f), 1.f);
                    hown = fmaf(z, hown - n, n);
                    mycur[j * 64 + u] = hown;
                }
            }
            __syncthreads();
            float* t_ = inp == in0 ? in1 : in0; inp = t_;
            t_ = mycur; mycur = myprv; myprv = t_;
        }
        // ---- head on h2(1023): hown holds it; same-wave LDS staging
        h2f[s][u] = hown;
        if (u < 5) {
            float acc = fc_b[u];
#pragma unroll
            for (int j = 0; j < 16; ++j)
                acc = fmaf(fc_w[u * 16 + j], h2f[s][j], acc);
            out[seq * 5 + u] = acc;
        }
    }
}

extern "C" void kernel_launch(void* const* d_in, const int* in_sizes, int n_in,
                              void* d_out, int out_size, void* d_ws, size_t ws_size,
                              hipStream_t stream) {
    const float* x      = (const float*)d_in[0];
    const float* w_ih0  = (const float*)d_in[1];
    const float* w_ih12 = (const float*)d_in[2];
    const float* w_hh   = (const float*)d_in[3];
    const float* b_ih   = (const float*)d_in[4];
    const float* b_hh   = (const float*)d_in[5];
    const float* fc_w   = (const float*)d_in[6];
    const float* fc_b   = (const float*)d_in[7];
    float* out = (float*)d_out;

    // 1024 blocks x 192 threads (3 waves: L0,L1,L2; 4 seqs/block)
    // -> 3072 waves -> 3 waves/SIMD, barrier domain = 3 waves.
    gru3_sk<<<1024, 192, 0, stream>>>(
        x, w_ih0, w_ih12, w_hh, b_ih, b_hh, fc_w, fc_b, out);
}